// Round 17
// baseline (185.767 us; speedup 1.0000x reference)
//
#include <hip/hip_runtime.h>

#define PLANE 65536
#define WIDTH 256
#define PADW 258
#define PADPLANE 66564   // 258*258

typedef __bf16 v8bf __attribute__((ext_vector_type(8)));
typedef float  v4f  __attribute__((ext_vector_type(4)));

typedef const __attribute__((address_space(1))) unsigned int* gas_ptr;
typedef __attribute__((address_space(3))) unsigned int* las_ptr;

// async global->LDS, 16 B per lane; LDS dest = wave-uniform base + lane*16
__device__ __forceinline__ void gl_lds(const void* g, void* l) {
  __builtin_amdgcn_global_load_lds((gas_ptr)g, (las_ptr)l, 16, 0, 0);
}

// self-inverse 16B-chunk swizzle within 8-chunk groups; ~0 conflicts measured
// (rounds 6-8 PMC).
__device__ __forceinline__ int swz(int c) {
  return (c & ~7) | ((c & 7) ^ ((c >> 3) & 7));
}

__device__ __forceinline__ unsigned int pack2(float a, float b) {
  __bf16 ba = (__bf16)a, bb = (__bf16)b;
  unsigned short sa = __builtin_bit_cast(unsigned short, ba);
  unsigned short sb = __builtin_bit_cast(unsigned short, bb);
  return (unsigned int)sa | ((unsigned int)sb << 16);
}

// ---------------------------------------------------------------------------
// wz_k: fused weight-prep + padding-ring zeroing (two independent ranges).
// ---------------------------------------------------------------------------
#define WT_N 37440                       // 288+18432+18432+288
#define ZR_N (8 * 1028 * 64)             // 16+32+16 uints per ring px
__global__ __launch_bounds__(256) void wz_k(
    const float* __restrict__ w1, const float* __restrict__ w2,
    const float* __restrict__ w3, const float* __restrict__ w4,
    float* __restrict__ w1t, __bf16* __restrict__ B2t,
    __bf16* __restrict__ B3t, float* __restrict__ w4t,
    __bf16* __restrict__ a1, __bf16* __restrict__ a2,
    __bf16* __restrict__ a3)
{
  int t = blockIdx.x * 256 + threadIdx.x;
  if (t < WT_N) {
    if (t < 288) {                       // w1: [32][1][9] -> [tap][32]
      int tap = t >> 5, cout = t & 31;
      w1t[t] = w1[cout * 9 + tap];
    }
    int t2 = t - 288;
    if (t2 >= 0 && t2 < 18432) {         // 64 x 288
      int cout = t2 / 288, k = t2 % 288;
      int tap = k / 32, cin = k % 32;
      B2t[t2] = (__bf16)w2[cout * 288 + cin * 9 + tap];
    }
    int t3 = t - (288 + 18432);
    if (t3 >= 0 && t3 < 18432) {         // 32 x 576
      int cout = t3 / 576, k = t3 % 576;
      int tap = k / 64, cin = k % 64;
      B3t[t3] = (__bf16)w3[cout * 576 + cin * 9 + tap];
    }
    int t4 = t - (288 + 18432 + 18432);
    if (t4 >= 0 && t4 < 288) {           // w4: [1][32][9] -> [tap][32]
      int tap = t4 >> 5, cin = t4 & 31;
      w4t[t4] = w4[cin * 9 + tap];
    }
    return;
  }
  int idx = t - WT_N;
  if (idx >= ZR_N) return;
  unsigned int* p; int C2;
  const int R1 = 8 * 1028 * 16, R2 = 8 * 1028 * 32;
  if (idx < R1)           { p = (unsigned int*)a1; C2 = 16; }
  else if (idx < R1 + R2) { p = (unsigned int*)a2; C2 = 32; idx -= R1; }
  else                    { p = (unsigned int*)a3; C2 = 16; idx -= R1 + R2; }
  int ch = idx % C2;
  int pr = idx / C2;                 // 0 .. 8*1028-1
  int b = pr / 1028, r = pr % 1028;
  int y, x;
  if      (r < 258) { y = 0;           x = r; }
  else if (r < 516) { y = 257;         x = r - 258; }
  else if (r < 772) { y = r - 516 + 1; x = 0; }
  else              { y = r - 772 + 1; x = 257; }
  p[((size_t)b * PADPLANE + y * PADW + x) * C2 + ch] = 0;
}

// ---------------------------------------------------------------------------
// prepconv1_k: fused prep + conv1. Thread = one pixel. Computes H, V, C_new
// (dout writes) AND conv1's 32 couts directly — vs taps computed on the fly
// as (inputs-H0)*(1/sf) with zero-padded loads.
// ---------------------------------------------------------------------------
__global__ __launch_bounds__(256) void prepconv1_k(
    const float* __restrict__ inputs, const float* __restrict__ H0,
    const float* __restrict__ C0, const float* __restrict__ c2p,
    const float* __restrict__ sfp, const float* __restrict__ w1t,
    const float* __restrict__ b1, float* __restrict__ dout,
    __bf16* __restrict__ act1)
{
  const int x = threadIdx.x, y = blockIdx.x, b = blockIdx.y;
  const int p = b * PLANE + y * WIDTH + x;
  const float c2 = c2p[0], sf = sfp[0], rsf = 1.0f / sf;

  float iv[3][3], hv[3][3];
  #pragma unroll
  for (int dy = 0; dy < 3; dy++) {
    int yy = y + dy - 1;
    #pragma unroll
    for (int dx = 0; dx < 3; dx++) {
      int xx = x + dx - 1;
      bool ok = (yy >= 0 && yy < 256 && xx >= 0 && xx < 256);
      int pn = p + (dy - 1) * WIDTH + (dx - 1);
      iv[dy][dx] = ok ? inputs[pn] : 0.f;
      hv[dy][dx] = ok ? H0[pn]     : 0.f;
    }
  }
  const float in = iv[1][1], h0 = hv[1][1];
  const float c0a = C0[b * 131072 + y * WIDTH + x];
  float lap = iv[0][1] + iv[2][1] + iv[1][0] + iv[1][2] - 4.f * in;
  float Hv = 2.f * in - c0a + c2 * lap;
  float V  = in - h0;
  dout[524288 + p]  = Hv;                               // H
  dout[2097152 + p] = V;                                // V
  dout[1048576 + b * 131072 + y * WIDTH + x]         = in;   // C_new[:,0]
  dout[1048576 + b * 131072 + 65536 + y * WIDTH + x] = c0a;  // C_new[:,1]

  float acc[32];
  #pragma unroll
  for (int i = 0; i < 32; i++) acc[i] = b1[i];
  #pragma unroll
  for (int tap = 0; tap < 9; tap++) {
    float v = (iv[tap / 3][tap % 3] - hv[tap / 3][tap % 3]) * rsf;
    const float* wp = w1t + tap * 32;                   // uniform
    #pragma unroll
    for (int i = 0; i < 32; i++) acc[i] = fmaf(wp[i], v, acc[i]);
  }
  unsigned int u[16];
  #pragma unroll
  for (int j = 0; j < 16; j++)
    u[j] = pack2(fmaxf(acc[2*j], 0.f), fmaxf(acc[2*j+1], 0.f));
  size_t pa = ((size_t)b * PADPLANE + (y+1) * PADW + (x+1)) * 32;
  uint4* op = reinterpret_cast<uint4*>(act1 + pa);
  #pragma unroll
  for (int j = 0; j < 4; j++)
    op[j] = make_uint4(u[4*j], u[4*j+1], u[4*j+2], u[4*j+3]);
}

// ---------------------------------------------------------------------------
// conv2 (32->64): single-barrier ring-4 pipeline (r16, validated): stage of
// row i+3 is issued BEFORE computing row i into a slot not read this phase;
// one barrier per row publishes it and protects the reclaimed slot.
// Operand swap (weights = A-operand, verified r10/11/14/15): lane's 4 acc
// values = 4 contiguous couts -> 8-B uint2 stores. Block = 4 waves = 4
// M-quarters of a 128-px x-tile; all 64 couts' weight fragments in regs.
// ROWS=4 -> 1024 blocks (ramp/tail fill; halo fetch 1.75x, latency-bound so
// cheap).
// ---------------------------------------------------------------------------
#define C2ROWB 8320   // 130 px * 32 ch * 2 B
template<int ROWS>
__global__ __launch_bounds__(256, 2) void conv2_k(
    const __bf16* __restrict__ in, const __bf16* __restrict__ Bt,
    const float* __restrict__ bias, __bf16* __restrict__ out)
{
  const int lane = threadIdx.x & 63, wave = threadIdx.x >> 6;
  const int l15 = lane & 15, q = lane >> 4;
  const int y0 = blockIdx.x * ROWS, xt = blockIdx.y, b = blockIdx.z;
  const int x0 = xt * 128;
  __shared__ __align__(16) char smem[4 * C2ROWB];
  const __bf16* plane = in + (size_t)b * PADPLANE * 32;

  auto stage = [&](int pr, char* lrow) {       // 130 px = 520 chunks, 130/wave
    const char* g = (const char*)(plane + ((size_t)pr * PADW + x0) * 32);
    const int base = wave * 130;
    #pragma unroll
    for (int j = 0; j < 2; j++) {
      int c = base + j * 64 + lane;
      gl_lds(g + (size_t)swz(c) * 16, lrow + (base + j * 64) * 16);
    }
    if (lane < 2) {
      int c = base + 128 + lane;
      gl_lds(g + (size_t)swz(c) * 16, lrow + (base + 128) * 16);
    }
  };

  v8bf breg[9][4];                             // weight A-fragments
  #pragma unroll
  for (int tap = 0; tap < 9; tap++)
    #pragma unroll
    for (int nt = 0; nt < 4; nt++)
      breg[tap][nt] = *(const v8bf*)(Bt + (size_t)(nt * 16 + l15) * 288
                                        + tap * 32 + q * 8);
  v4f bv[4];
  #pragma unroll
  for (int nt = 0; nt < 4; nt++) bv[nt] = *(const v4f*)(bias + nt * 16 + q * 4);

  // prologue: rows y0..y0+2 into slots 0..2 (slot = (row-y0) & 3)
  #pragma unroll
  for (int r = 0; r < 3; r++) stage(y0 + r, smem + r * C2ROWB);
  __syncthreads();

  for (int i = 0; i < ROWS; i++) {
    // stage row i+3 into slot (i+3)&3 — not read this phase; overlaps MFMA
    if (i + 3 < ROWS + 2)
      stage(y0 + i + 3, smem + ((i + 3) & 3) * C2ROWB);

    v4f acc[2][4];
    #pragma unroll
    for (int mt = 0; mt < 2; mt++)
      #pragma unroll
      for (int nt = 0; nt < 4; nt++)
        acc[mt][nt] = bv[nt];

    #pragma unroll
    for (int tap = 0; tap < 9; tap++) {
      const int dy = tap / 3, dx = tap % 3;
      const char* srow = smem + ((i + dy) & 3) * C2ROWB;
      v8bf af[2];
      #pragma unroll
      for (int mt = 0; mt < 2; mt++) {
        int P = wave * 32 + mt * 16 + l15 + dx;      // 0..129
        af[mt] = *(const v8bf*)(srow + (size_t)swz(P * 4 + q) * 16);
      }
      #pragma unroll
      for (int mt = 0; mt < 2; mt++)
        #pragma unroll
        for (int nt = 0; nt < 4; nt++)
          acc[mt][nt] = __builtin_amdgcn_mfma_f32_16x16x32_bf16(
              breg[tap][nt], af[mt], acc[mt][nt], 0, 0, 0);
    }
    // store: lane holds couts nt*16+q*4..+3 at px = x0+1 + wave*32+mt*16+l15
    {
      size_t rb = ((size_t)b * PADPLANE + (size_t)(y0 + i + 1) * PADW
                   + x0 + 1) * 64;
      #pragma unroll
      for (int mt = 0; mt < 2; mt++) {
        size_t pa = rb + (size_t)(wave * 32 + mt * 16 + l15) * 64;
        #pragma unroll
        for (int nt = 0; nt < 4; nt++) {
          float r0 = fmaxf(acc[mt][nt][0], 0.f);
          float r1 = fmaxf(acc[mt][nt][1], 0.f);
          float r2 = fmaxf(acc[mt][nt][2], 0.f);
          float r3 = fmaxf(acc[mt][nt][3], 0.f);
          *(uint2*)(out + pa + nt * 16 + q * 4) =
              make_uint2(pack2(r0, r1), pack2(r2, r3));
        }
      }
    }
    __syncthreads();   // publish staged row i+3; protect slot reclaimed next
  }
}

// ---------------------------------------------------------------------------
// conv3 (64->32), round-17: x-tile 128, RING-3, NO pairing, mt=2 — the
// pairing variants all need ring-4+ (>=66.5 KB -> 2 blocks/CU). Ring-3 is
// 49.9 KB -> 3 blocks/CU, and acc drops to 16 regs, so co-residency (not
// per-row LDS-read savings) covers the barrier drains. ROWS=4 -> 1024
// blocks. Operand-swap stores (8-B uint2, verified r14/15/16).
// ---------------------------------------------------------------------------
#define C3ROWB 16640   // 130 px * 64 ch * 2 B
template<int ROWS>
__global__ __launch_bounds__(256, 2) void conv3_k(
    const __bf16* __restrict__ in, const __bf16* __restrict__ Bt,
    const float* __restrict__ bias, __bf16* __restrict__ out)
{
  const int lane = threadIdx.x & 63, wave = threadIdx.x >> 6;
  const int l15 = lane & 15, q = lane >> 4;
  const int y0 = blockIdx.x * ROWS, xt = blockIdx.y, b = blockIdx.z;
  const int x0 = xt * 128;
  __shared__ __align__(16) char smem[3 * C3ROWB];
  const __bf16* plane = in + (size_t)b * PADPLANE * 64;

  auto stage = [&](int pr, char* lrow) {       // 130 px = 1040 chunks, 260/wave
    const char* g = (const char*)(plane + ((size_t)pr * PADW + x0) * 64);
    const int base = wave * 260;
    #pragma unroll
    for (int j = 0; j < 4; j++) {
      int c = base + j * 64 + lane;
      gl_lds(g + (size_t)swz(c) * 16, lrow + (base + j * 64) * 16);
    }
    if (lane < 4) {
      int c = base + 256 + lane;
      gl_lds(g + (size_t)swz(c) * 16, lrow + (base + 256) * 16);
    }
  };

  v8bf breg[9][2][2];                          // tap, kb, nt (weight A-frags)
  #pragma unroll
  for (int tap = 0; tap < 9; tap++)
    #pragma unroll
    for (int kb = 0; kb < 2; kb++)
      #pragma unroll
      for (int nt = 0; nt < 2; nt++)
        breg[tap][kb][nt] = *(const v8bf*)(Bt + (size_t)(nt * 16 + l15) * 576
                                              + tap * 64 + kb * 32 + q * 8);
  v4f bv[2];
  #pragma unroll
  for (int nt = 0; nt < 2; nt++) bv[nt] = *(const v4f*)(bias + nt * 16 + q * 4);

  #pragma unroll
  for (int r = 0; r < 3; r++) stage(y0 + r, smem + r * C3ROWB);
  __syncthreads();

  for (int i = 0; i < ROWS; i++) {
    v4f acc[2][2];                             // mt, nt
    #pragma unroll
    for (int mt = 0; mt < 2; mt++)
      #pragma unroll
      for (int nt = 0; nt < 2; nt++)
        acc[mt][nt] = bv[nt];

    #pragma unroll
    for (int tap = 0; tap < 9; tap++) {
      const int dy = tap / 3, dx = tap % 3;
      const char* srow = smem + ((i + dy) % 3) * C3ROWB;
      #pragma unroll
      for (int kb = 0; kb < 2; kb++) {
        v8bf af[2];
        #pragma unroll
        for (int mt = 0; mt < 2; mt++) {
          int P = wave * 32 + mt * 16 + l15 + dx;   // 0..129
          af[mt] = *(const v8bf*)(srow + (size_t)swz(P * 8 + kb * 4 + q) * 16);
        }
        #pragma unroll
        for (int mt = 0; mt < 2; mt++)
          #pragma unroll
          for (int nt = 0; nt < 2; nt++)
            acc[mt][nt] = __builtin_amdgcn_mfma_f32_16x16x32_bf16(
                breg[tap][kb][nt], af[mt], acc[mt][nt], 0, 0, 0);
      }
    }
    // store: lane holds couts nt*16+q*4..+3 at px = x0+1 + wave*32+mt*16+l15
    {
      size_t rb = ((size_t)b * PADPLANE + (size_t)(y0 + i + 1) * PADW
                   + x0 + 1) * 32;
      #pragma unroll
      for (int mt = 0; mt < 2; mt++) {
        size_t pa = rb + (size_t)(wave * 32 + mt * 16 + l15) * 32;
        #pragma unroll
        for (int nt = 0; nt < 2; nt++) {
          float r0 = fmaxf(acc[mt][nt][0], 0.f);
          float r1 = fmaxf(acc[mt][nt][1], 0.f);
          float r2 = fmaxf(acc[mt][nt][2], 0.f);
          float r3 = fmaxf(acc[mt][nt][3], 0.f);
          *(uint2*)(out + pa + nt * 16 + q * 4) =
              make_uint2(pack2(r0, r1), pack2(r2, r3));
        }
      }
    }
    __syncthreads();                       // readers done with slot i%3
    if (i + 3 < ROWS + 2)
      stage(y0 + i + 3, smem + (i % 3) * C3ROWB);
    __syncthreads();                       // staged row visible
  }
}

// ---------------------------------------------------------------------------
// conv4 (32->1): 2 output rows/block (grid 1024 -> 16 waves/CU), straight-
// line dual accumulators; 12x uint4 loads batch per row-step.
// Fused epilogue: V_hat = (conv+b4)*sf ; outputs = H + V_hat.
// ---------------------------------------------------------------------------
__global__ __launch_bounds__(256) void conv4_k(
    const __bf16* __restrict__ act3, const float* __restrict__ w4t,
    const float* __restrict__ b4, const float* __restrict__ sfp,
    float* __restrict__ dout)
{
  const int x = threadIdx.x, y0 = blockIdx.x * 2, b = blockIdx.y;
  const float b4v = b4[0], sf = sfp[0];
  const uint4* base = (const uint4*)(act3 + (size_t)b * PADPLANE * 32);
  float acc0 = b4v, acc1 = b4v;

  #pragma unroll
  for (int t = 0; t < 4; t++) {
    const uint4* rp = base + ((size_t)(y0 + t) * PADW + x) * 4;  // 4 uint4/px
    uint4 L[12];
    #pragma unroll
    for (int j = 0; j < 12; j++) L[j] = rp[j];
    #pragma unroll
    for (int j = 0; j < 12; j++) {
      const int dx = j >> 2, c0 = (j & 3) * 8;
      unsigned int uu[4] = {L[j].x, L[j].y, L[j].z, L[j].w};
      float f[8];
      #pragma unroll
      for (int k = 0; k < 4; k++) {
        f[2*k]   = __builtin_bit_cast(float, uu[k] << 16);
        f[2*k+1] = __builtin_bit_cast(float, uu[k] & 0xFFFF0000u);
      }
      if (t <= 2) {
        const float* wp = w4t + (t * 3 + dx) * 32 + c0;          // uniform
        #pragma unroll
        for (int k = 0; k < 8; k++) acc0 = fmaf(wp[k], f[k], acc0);
      }
      if (t >= 1) {
        const float* wp = w4t + ((t - 1) * 3 + dx) * 32 + c0;    // uniform
        #pragma unroll
        for (int k = 0; k < 8; k++) acc1 = fmaf(wp[k], f[k], acc1);
      }
    }
  }
  size_t p0 = ((size_t)b << 16) + (size_t)y0 * WIDTH + x;
  float vh0 = acc0 * sf, vh1 = acc1 * sf;
  dout[p0]                   = dout[524288 + p0] + vh0;          // outputs
  dout[2621440 + p0]         = vh0;                              // V_hat
  dout[p0 + WIDTH]           = dout[524288 + p0 + WIDTH] + vh1;
  dout[2621440 + p0 + WIDTH] = vh1;
}

// ---------------------------------------------------------------------------
extern "C" void kernel_launch(void* const* d_in, const int* in_sizes, int n_in,
                              void* d_out, int out_size, void* d_ws, size_t ws_size,
                              hipStream_t stream) {
  const float* inputs = (const float*)d_in[0];
  const float* H0     = (const float*)d_in[1];
  const float* C0     = (const float*)d_in[2];
  const float* c2     = (const float*)d_in[3];
  const float* sf     = (const float*)d_in[4];
  const float* w1     = (const float*)d_in[5];
  const float* b1     = (const float*)d_in[6];
  const float* w2     = (const float*)d_in[7];
  const float* b2     = (const float*)d_in[8];
  const float* w3     = (const float*)d_in[9];
  const float* b3     = (const float*)d_in[10];
  const float* w4     = (const float*)d_in[11];
  const float* b4     = (const float*)d_in[12];
  float* out = (float*)d_out;
  float* ws  = (float*)d_ws;

  float*  w1t  = ws;                               // 288 fp32
  float*  w4t  = ws + 288;                         // 288 fp32
  __bf16* B2t  = (__bf16*)(ws + 576);              // 18432 bf16
  __bf16* B3t  = (__bf16*)(ws + 9792);             // 18432 bf16
  __bf16* act1 = (__bf16*)(ws + 19008);            // 8*66564*32 bf16
  __bf16* act2 = act1 + (size_t)8 * PADPLANE * 32; // 8*66564*64 bf16
  __bf16* act3 = act2 + (size_t)8 * PADPLANE * 64; // 8*66564*32 bf16

  wz_k<<<2203, 256, 0, stream>>>(w1, w2, w3, w4, w1t, B2t, B3t, w4t,
                                 act1, act2, act3);
  prepconv1_k<<<dim3(256, 8), 256, 0, stream>>>(inputs, H0, C0, c2, sf,
                                                w1t, b1, out, act1);
  conv2_k<4><<<dim3(64, 2, 8), 256, 0, stream>>>(act1, B2t, b2, act2);
  conv3_k<4><<<dim3(64, 2, 8), 256, 0, stream>>>(act2, B3t, b3, act3);
  conv4_k<<<dim3(128, 8), 256, 0, stream>>>(act3, w4t, b4, sf, out);
}

// Round 18
// 170.434 us; speedup vs baseline: 1.0900x; 1.0900x over previous
//
#include <hip/hip_runtime.h>

#define PLANE 65536
#define WIDTH 256
#define PADW 258
#define PADPLANE 66564   // 258*258

typedef __bf16 v8bf __attribute__((ext_vector_type(8)));
typedef float  v4f  __attribute__((ext_vector_type(4)));

typedef const __attribute__((address_space(1))) unsigned int* gas_ptr;
typedef __attribute__((address_space(3))) unsigned int* las_ptr;

// async global->LDS, 16 B per lane; LDS dest = wave-uniform base + lane*16
__device__ __forceinline__ void gl_lds(const void* g, void* l) {
  __builtin_amdgcn_global_load_lds((gas_ptr)g, (las_ptr)l, 16, 0, 0);
}

// self-inverse 16B-chunk swizzle within 8-chunk groups; ~0 conflicts measured
// (rounds 6-8 PMC).
__device__ __forceinline__ int swz(int c) {
  return (c & ~7) | ((c & 7) ^ ((c >> 3) & 7));
}

__device__ __forceinline__ unsigned int pack2(float a, float b) {
  __bf16 ba = (__bf16)a, bb = (__bf16)b;
  unsigned short sa = __builtin_bit_cast(unsigned short, ba);
  unsigned short sb = __builtin_bit_cast(unsigned short, bb);
  return (unsigned int)sa | ((unsigned int)sb << 16);
}

// ---------------------------------------------------------------------------
// wz_k: fused weight-prep + padding-ring zeroing (two independent ranges).
// ---------------------------------------------------------------------------
#define WT_N 37440                       // 288+18432+18432+288
#define ZR_N (8 * 1028 * 64)             // 16+32+16 uints per ring px
__global__ __launch_bounds__(256) void wz_k(
    const float* __restrict__ w1, const float* __restrict__ w2,
    const float* __restrict__ w3, const float* __restrict__ w4,
    float* __restrict__ w1t, __bf16* __restrict__ B2t,
    __bf16* __restrict__ B3t, float* __restrict__ w4t,
    __bf16* __restrict__ a1, __bf16* __restrict__ a2,
    __bf16* __restrict__ a3)
{
  int t = blockIdx.x * 256 + threadIdx.x;
  if (t < WT_N) {
    if (t < 288) {                       // w1: [32][1][9] -> [tap][32]
      int tap = t >> 5, cout = t & 31;
      w1t[t] = w1[cout * 9 + tap];
    }
    int t2 = t - 288;
    if (t2 >= 0 && t2 < 18432) {         // 64 x 288
      int cout = t2 / 288, k = t2 % 288;
      int tap = k / 32, cin = k % 32;
      B2t[t2] = (__bf16)w2[cout * 288 + cin * 9 + tap];
    }
    int t3 = t - (288 + 18432);
    if (t3 >= 0 && t3 < 18432) {         // 32 x 576
      int cout = t3 / 576, k = t3 % 576;
      int tap = k / 64, cin = k % 64;
      B3t[t3] = (__bf16)w3[cout * 576 + cin * 9 + tap];
    }
    int t4 = t - (288 + 18432 + 18432);
    if (t4 >= 0 && t4 < 288) {           // w4: [1][32][9] -> [tap][32]
      int tap = t4 >> 5, cin = t4 & 31;
      w4t[t4] = w4[cin * 9 + tap];
    }
    return;
  }
  int idx = t - WT_N;
  if (idx >= ZR_N) return;
  unsigned int* p; int C2;
  const int R1 = 8 * 1028 * 16, R2 = 8 * 1028 * 32;
  if (idx < R1)           { p = (unsigned int*)a1; C2 = 16; }
  else if (idx < R1 + R2) { p = (unsigned int*)a2; C2 = 32; idx -= R1; }
  else                    { p = (unsigned int*)a3; C2 = 16; idx -= R1 + R2; }
  int ch = idx % C2;
  int pr = idx / C2;                 // 0 .. 8*1028-1
  int b = pr / 1028, r = pr % 1028;
  int y, x;
  if      (r < 258) { y = 0;           x = r; }
  else if (r < 516) { y = 257;         x = r - 258; }
  else if (r < 772) { y = r - 516 + 1; x = 0; }
  else              { y = r - 772 + 1; x = 257; }
  p[((size_t)b * PADPLANE + y * PADW + x) * C2 + ch] = 0;
}

// ---------------------------------------------------------------------------
// prepconv1_k: fused prep + conv1. Thread = one pixel. Computes H, V, C_new
// (dout writes) AND conv1's 32 couts directly — vs taps computed on the fly
// as (inputs-H0)*(1/sf) with zero-padded loads.
// ---------------------------------------------------------------------------
__global__ __launch_bounds__(256) void prepconv1_k(
    const float* __restrict__ inputs, const float* __restrict__ H0,
    const float* __restrict__ C0, const float* __restrict__ c2p,
    const float* __restrict__ sfp, const float* __restrict__ w1t,
    const float* __restrict__ b1, float* __restrict__ dout,
    __bf16* __restrict__ act1)
{
  const int x = threadIdx.x, y = blockIdx.x, b = blockIdx.y;
  const int p = b * PLANE + y * WIDTH + x;
  const float c2 = c2p[0], sf = sfp[0], rsf = 1.0f / sf;

  float iv[3][3], hv[3][3];
  #pragma unroll
  for (int dy = 0; dy < 3; dy++) {
    int yy = y + dy - 1;
    #pragma unroll
    for (int dx = 0; dx < 3; dx++) {
      int xx = x + dx - 1;
      bool ok = (yy >= 0 && yy < 256 && xx >= 0 && xx < 256);
      int pn = p + (dy - 1) * WIDTH + (dx - 1);
      iv[dy][dx] = ok ? inputs[pn] : 0.f;
      hv[dy][dx] = ok ? H0[pn]     : 0.f;
    }
  }
  const float in = iv[1][1], h0 = hv[1][1];
  const float c0a = C0[b * 131072 + y * WIDTH + x];
  float lap = iv[0][1] + iv[2][1] + iv[1][0] + iv[1][2] - 4.f * in;
  float Hv = 2.f * in - c0a + c2 * lap;
  float V  = in - h0;
  dout[524288 + p]  = Hv;                               // H
  dout[2097152 + p] = V;                                // V
  dout[1048576 + b * 131072 + y * WIDTH + x]         = in;   // C_new[:,0]
  dout[1048576 + b * 131072 + 65536 + y * WIDTH + x] = c0a;  // C_new[:,1]

  float acc[32];
  #pragma unroll
  for (int i = 0; i < 32; i++) acc[i] = b1[i];
  #pragma unroll
  for (int tap = 0; tap < 9; tap++) {
    float v = (iv[tap / 3][tap % 3] - hv[tap / 3][tap % 3]) * rsf;
    const float* wp = w1t + tap * 32;                   // uniform
    #pragma unroll
    for (int i = 0; i < 32; i++) acc[i] = fmaf(wp[i], v, acc[i]);
  }
  unsigned int u[16];
  #pragma unroll
  for (int j = 0; j < 16; j++)
    u[j] = pack2(fmaxf(acc[2*j], 0.f), fmaxf(acc[2*j+1], 0.f));
  size_t pa = ((size_t)b * PADPLANE + (y+1) * PADW + (x+1)) * 32;
  uint4* op = reinterpret_cast<uint4*>(act1 + pa);
  #pragma unroll
  for (int j = 0; j < 4; j++)
    op[j] = make_uint4(u[4*j], u[4*j+1], u[4*j+2], u[4*j+3]);
}

// ---------------------------------------------------------------------------
// conv2 (32->64): block = 4 waves = 4 disjoint M-quarters of a 128-px x-tile;
// each wave holds ALL 64 couts' B-fragments in registers (NT=4).
// (round-13 measured-best form)
// ---------------------------------------------------------------------------
#define C2ROWB 8320   // 130 px * 32 ch * 2 B
template<int ROWS>
__global__ __launch_bounds__(256, 2) void conv2_k(
    const __bf16* __restrict__ in, const __bf16* __restrict__ Bt,
    const float* __restrict__ bias, __bf16* __restrict__ out)
{
  const int lane = threadIdx.x & 63, wave = threadIdx.x >> 6;
  const int l15 = lane & 15, q = lane >> 4;
  const int y0 = blockIdx.x * ROWS, xt = blockIdx.y, b = blockIdx.z;
  const int x0 = xt * 128;
  __shared__ __align__(16) char smem[3 * C2ROWB];
  const __bf16* plane = in + (size_t)b * PADPLANE * 32;

  auto stage = [&](int pr, char* lrow) {       // 130 px = 520 chunks, 130/wave
    const char* g = (const char*)(plane + ((size_t)pr * PADW + x0) * 32);
    const int base = wave * 130;
    #pragma unroll
    for (int j = 0; j < 2; j++) {
      int c = base + j * 64 + lane;
      gl_lds(g + (size_t)swz(c) * 16, lrow + (base + j * 64) * 16);
    }
    if (lane < 2) {
      int c = base + 128 + lane;
      gl_lds(g + (size_t)swz(c) * 16, lrow + (base + 128) * 16);
    }
  };

  v8bf breg[9][4];
  #pragma unroll
  for (int tap = 0; tap < 9; tap++)
    #pragma unroll
    for (int nt = 0; nt < 4; nt++)
      breg[tap][nt] = *(const v8bf*)(Bt + (size_t)(nt * 16 + l15) * 288
                                        + tap * 32 + q * 8);
  float bv[4];
  #pragma unroll
  for (int nt = 0; nt < 4; nt++) bv[nt] = bias[nt * 16 + l15];

  #pragma unroll
  for (int r = 0; r < 3; r++) stage(y0 + r, smem + r * C2ROWB);
  __syncthreads();

  for (int i = 0; i < ROWS; i++) {
    v4f acc[2][4];
    #pragma unroll
    for (int mt = 0; mt < 2; mt++)
      #pragma unroll
      for (int nt = 0; nt < 4; nt++)
        acc[mt][nt] = (v4f){bv[nt], bv[nt], bv[nt], bv[nt]};

    #pragma unroll
    for (int tap = 0; tap < 9; tap++) {
      const int dy = tap / 3, dx = tap % 3;
      const char* srow = smem + ((i + dy) % 3) * C2ROWB;
      v8bf af[2];
      #pragma unroll
      for (int mt = 0; mt < 2; mt++) {
        int P = wave * 32 + mt * 16 + l15 + dx;      // 0..129
        af[mt] = *(const v8bf*)(srow + (size_t)swz(P * 4 + q) * 16);
      }
      #pragma unroll
      for (int mt = 0; mt < 2; mt++)
        #pragma unroll
        for (int nt = 0; nt < 4; nt++)
          acc[mt][nt] = __builtin_amdgcn_mfma_f32_16x16x32_bf16(
              af[mt], breg[tap][nt], acc[mt][nt], 0, 0, 0);
    }
    {
      size_t rb = ((size_t)b * PADPLANE + (size_t)(y0 + i + 1) * PADW
                   + x0 + 1) * 64;
      #pragma unroll
      for (int mt = 0; mt < 2; mt++) {
        #pragma unroll
        for (int r = 0; r < 4; r++) {
          size_t pa = rb + (size_t)(wave * 32 + mt * 16 + q * 4 + r) * 64;
          #pragma unroll
          for (int nt = 0; nt < 4; nt++)
            out[pa + nt * 16 + l15] = (__bf16)fmaxf(acc[mt][nt][r], 0.f);
        }
      }
    }
    __syncthreads();
    if (i + 3 < ROWS + 2)
      stage(y0 + i + 3, smem + (i % 3) * C2ROWB);
    __syncthreads();
  }
}

// ---------------------------------------------------------------------------
// conv3 (64->32): NT=2 (all 32 couts in regs) + row-pairing over a 4-row
// act2 ring: each A-fragment feeds two output rows (taps dy / dy-1).
// (round-13 measured-best form)
// ---------------------------------------------------------------------------
#define C3ROWB 16640   // 130 px * 64 ch * 2 B
template<int ROWS>     // even
__global__ __launch_bounds__(256, 2) void conv3_k(
    const __bf16* __restrict__ in, const __bf16* __restrict__ Bt,
    const float* __restrict__ bias, __bf16* __restrict__ out)
{
  const int lane = threadIdx.x & 63, wave = threadIdx.x >> 6;
  const int l15 = lane & 15, q = lane >> 4;
  const int y0 = blockIdx.x * ROWS, xt = blockIdx.y, b = blockIdx.z;
  const int x0 = xt * 128;
  __shared__ __align__(16) char smem[4 * C3ROWB];
  const __bf16* plane = in + (size_t)b * PADPLANE * 64;

  auto stage = [&](int pr, char* lrow) {       // 130 px = 1040 chunks, 260/wave
    const char* g = (const char*)(plane + ((size_t)pr * PADW + x0) * 64);
    const int base = wave * 260;
    #pragma unroll
    for (int j = 0; j < 4; j++) {
      int c = base + j * 64 + lane;
      gl_lds(g + (size_t)swz(c) * 16, lrow + (base + j * 64) * 16);
    }
    if (lane < 4) {
      int c = base + 256 + lane;
      gl_lds(g + (size_t)swz(c) * 16, lrow + (base + 256) * 16);
    }
  };

  v8bf breg[9][2][2];                          // tap, kb, nt
  #pragma unroll
  for (int tap = 0; tap < 9; tap++)
    #pragma unroll
    for (int kb = 0; kb < 2; kb++)
      #pragma unroll
      for (int nt = 0; nt < 2; nt++)
        breg[tap][kb][nt] = *(const v8bf*)(Bt + (size_t)(nt * 16 + l15) * 576
                                              + tap * 64 + kb * 32 + q * 8);
  float bv[2] = {bias[l15], bias[16 + l15]};

  #pragma unroll
  for (int r = 0; r < 4; r++) stage(y0 + r, smem + r * C3ROWB);
  __syncthreads();

  for (int ps = 0; ps < ROWS / 2; ps++) {      // output rows r0=y0+2ps, r0+1
    v4f acc[2][2][2];                          // rr, mt, nt
    #pragma unroll
    for (int rr = 0; rr < 2; rr++)
      #pragma unroll
      for (int mt = 0; mt < 2; mt++)
        #pragma unroll
        for (int nt = 0; nt < 2; nt++)
          acc[rr][mt][nt] = (v4f){bv[nt], bv[nt], bv[nt], bv[nt]};

    #pragma unroll
    for (int t = 0; t < 4; t++) {              // act2 ring row = padded y0+2ps+t
      const char* srow = smem + ((2 * ps + t) & 3) * C3ROWB;
      #pragma unroll
      for (int dx = 0; dx < 3; dx++) {
        #pragma unroll
        for (int kb = 0; kb < 2; kb++) {
          v8bf af[2];
          #pragma unroll
          for (int mt = 0; mt < 2; mt++) {
            int P = wave * 32 + mt * 16 + l15 + dx;   // 0..129
            af[mt] = *(const v8bf*)(srow + (size_t)swz(P * 8 + kb * 4 + q) * 16);
          }
          #pragma unroll
          for (int mt = 0; mt < 2; mt++)
            #pragma unroll
            for (int nt = 0; nt < 2; nt++) {
              if (t <= 2)                       // row r0, tap dy = t
                acc[0][mt][nt] = __builtin_amdgcn_mfma_f32_16x16x32_bf16(
                    af[mt], breg[t * 3 + dx][kb][nt], acc[0][mt][nt], 0, 0, 0);
              if (t >= 1)                       // row r1, tap dy = t-1
                acc[1][mt][nt] = __builtin_amdgcn_mfma_f32_16x16x32_bf16(
                    af[mt], breg[(t - 1) * 3 + dx][kb][nt], acc[1][mt][nt],
                    0, 0, 0);
            }
        }
      }
    }
    {
      #pragma unroll
      for (int rr = 0; rr < 2; rr++) {
        size_t rb = ((size_t)b * PADPLANE
                     + (size_t)(y0 + 2 * ps + rr + 1) * PADW + x0 + 1) * 32;
        #pragma unroll
        for (int mt = 0; mt < 2; mt++) {
          #pragma unroll
          for (int r = 0; r < 4; r++) {
            size_t pa = rb + (size_t)(wave * 32 + mt * 16 + q * 4 + r) * 32;
            #pragma unroll
            for (int nt = 0; nt < 2; nt++)
              out[pa + nt * 16 + l15] = (__bf16)fmaxf(acc[rr][mt][nt][r], 0.f);
          }
        }
      }
    }
    __syncthreads();
    if (ps + 1 < ROWS / 2) {                   // stage rows 2ps+4, 2ps+5
      stage(y0 + 2 * ps + 4, smem + ((2 * ps) & 3) * C3ROWB);
      stage(y0 + 2 * ps + 5, smem + ((2 * ps + 1) & 3) * C3ROWB);
    }
    __syncthreads();
  }
}

// ---------------------------------------------------------------------------
// conv4 (32->1): 2 output rows/block (grid 1024 -> 16 waves/CU), straight-
// line dual accumulators; 12x uint4 loads batch per row-step.
// Fused epilogue: V_hat = (conv+b4)*sf ; outputs = H + V_hat.
// ---------------------------------------------------------------------------
__global__ __launch_bounds__(256) void conv4_k(
    const __bf16* __restrict__ act3, const float* __restrict__ w4t,
    const float* __restrict__ b4, const float* __restrict__ sfp,
    float* __restrict__ dout)
{
  const int x = threadIdx.x, y0 = blockIdx.x * 2, b = blockIdx.y;
  const float b4v = b4[0], sf = sfp[0];
  const uint4* base = (const uint4*)(act3 + (size_t)b * PADPLANE * 32);
  float acc0 = b4v, acc1 = b4v;

  #pragma unroll
  for (int t = 0; t < 4; t++) {
    const uint4* rp = base + ((size_t)(y0 + t) * PADW + x) * 4;  // 4 uint4/px
    uint4 L[12];
    #pragma unroll
    for (int j = 0; j < 12; j++) L[j] = rp[j];
    #pragma unroll
    for (int j = 0; j < 12; j++) {
      const int dx = j >> 2, c0 = (j & 3) * 8;
      unsigned int uu[4] = {L[j].x, L[j].y, L[j].z, L[j].w};
      float f[8];
      #pragma unroll
      for (int k = 0; k < 4; k++) {
        f[2*k]   = __builtin_bit_cast(float, uu[k] << 16);
        f[2*k+1] = __builtin_bit_cast(float, uu[k] & 0xFFFF0000u);
      }
      if (t <= 2) {
        const float* wp = w4t + (t * 3 + dx) * 32 + c0;          // uniform
        #pragma unroll
        for (int k = 0; k < 8; k++) acc0 = fmaf(wp[k], f[k], acc0);
      }
      if (t >= 1) {
        const float* wp = w4t + ((t - 1) * 3 + dx) * 32 + c0;    // uniform
        #pragma unroll
        for (int k = 0; k < 8; k++) acc1 = fmaf(wp[k], f[k], acc1);
      }
    }
  }
  size_t p0 = ((size_t)b << 16) + (size_t)y0 * WIDTH + x;
  float vh0 = acc0 * sf, vh1 = acc1 * sf;
  dout[p0]                   = dout[524288 + p0] + vh0;          // outputs
  dout[2621440 + p0]         = vh0;                              // V_hat
  dout[p0 + WIDTH]           = dout[524288 + p0 + WIDTH] + vh1;
  dout[2621440 + p0 + WIDTH] = vh1;
}

// ---------------------------------------------------------------------------
extern "C" void kernel_launch(void* const* d_in, const int* in_sizes, int n_in,
                              void* d_out, int out_size, void* d_ws, size_t ws_size,
                              hipStream_t stream) {
  const float* inputs = (const float*)d_in[0];
  const float* H0     = (const float*)d_in[1];
  const float* C0     = (const float*)d_in[2];
  const float* c2     = (const float*)d_in[3];
  const float* sf     = (const float*)d_in[4];
  const float* w1     = (const float*)d_in[5];
  const float* b1     = (const float*)d_in[6];
  const float* w2     = (const float*)d_in[7];
  const float* b2     = (const float*)d_in[8];
  const float* w3     = (const float*)d_in[9];
  const float* b3     = (const float*)d_in[10];
  const float* w4     = (const float*)d_in[11];
  const float* b4     = (const float*)d_in[12];
  float* out = (float*)d_out;
  float* ws  = (float*)d_ws;

  float*  w1t  = ws;                               // 288 fp32
  float*  w4t  = ws + 288;                         // 288 fp32
  __bf16* B2t  = (__bf16*)(ws + 576);              // 18432 bf16
  __bf16* B3t  = (__bf16*)(ws + 9792);             // 18432 bf16
  __bf16* act1 = (__bf16*)(ws + 19008);            // 8*66564*32 bf16
  __bf16* act2 = act1 + (size_t)8 * PADPLANE * 32; // 8*66564*64 bf16
  __bf16* act3 = act2 + (size_t)8 * PADPLANE * 64; // 8*66564*32 bf16

  wz_k<<<2203, 256, 0, stream>>>(w1, w2, w3, w4, w1t, B2t, B3t, w4t,
                                 act1, act2, act3);
  prepconv1_k<<<dim3(256, 8), 256, 0, stream>>>(inputs, H0, C0, c2, sf,
                                                w1t, b1, out, act1);
  conv2_k<8><<<dim3(32, 2, 8), 256, 0, stream>>>(act1, B2t, b2, act2);
  conv3_k<8><<<dim3(32, 2, 8), 256, 0, stream>>>(act2, B3t, b3, act3);
  conv4_k<<<dim3(128, 8), 256, 0, stream>>>(act3, w4t, b4, sf, out);
}